// Round 10
// baseline (1555.990 us; speedup 1.0000x reference)
//
#include <hip/hip_runtime.h>
#include <hip/hip_bf16.h>

#define NHEAD 4
#define NT 256
#define NB 2048  // 8 blocks/CU * 256 CU; co-residency forced by launch_bounds(256,8)

typedef __hip_bfloat16 bf16;
typedef __hip_bfloat162 bf162;
typedef float f32x4 __attribute__((ext_vector_type(4)));

__device__ __forceinline__ float dot8(uint4 a, uint4 b) {
  const unsigned* pa = &a.x;
  const unsigned* pb = &b.x;
  float acc = 0.f;
#pragma unroll
  for (int i = 0; i < 4; ++i) {
    const float2 fa = __bfloat1622float2(*(const bf162*)&pa[i]);
    const float2 fb = __bfloat1622float2(*(const bf162*)&pb[i]);
    acc = fmaf(fa.x, fb.x, acc);
    acc = fmaf(fa.y, fb.y, acc);
  }
  return acc;
}

// Agent-scope grid barrier. All NB blocks are co-resident (launch_bounds
// guarantees 8 waves/SIMD => 8x256-thread blocks per CU => NB fit exactly),
// so spinning is deadlock-free. The release/acquire fences emit the L2
// writeback/invalidate that makes cross-XCD stores visible (G16).
__device__ __forceinline__ void grid_barrier(unsigned* counter, unsigned target) {
  __syncthreads();
  if (threadIdx.x == 0) {
    __threadfence();  // release: writeback dirty L2 (q/k/prods/denom-zeros)
    __hip_atomic_fetch_add(counter, 1u, __ATOMIC_ACQ_REL, __HIP_MEMORY_SCOPE_AGENT);
    while (__hip_atomic_load(counter, __ATOMIC_ACQUIRE, __HIP_MEMORY_SCOPE_AGENT) < target)
      __builtin_amdgcn_s_sleep(2);
    __threadfence();  // acquire: invalidate L1/L2 before post-barrier reads
  }
  __syncthreads();
}

// ---------------------------------------------------------------------------
// ONE persistent kernel, three phases separated by grid barriers:
//  P1: QKV projection (R6's proven 16-node-tile body, grid-strided over
//      tiles) + denom zeroing.  q,k bf16 [N][64]; v fp32 -> out [N,d,h].
//  P2: edge dots + denom atomics -- R6's exact mapping: thread=(edge,head),
//      4 lanes/edge read one contiguous 128B row; atomics to denom[src*4+h]
//      (interleaved layout: 4 same-line atomics/edge = 1.6M line-touches,
//      the measured ~1.86e10/s wall => ~86us floor). prods written in final
//      [E][4] position.
//  P3: normalize: attn = exp(prods) / (denom[seg]+eps), 16B NT stores.
// ---------------------------------------------------------------------------
__global__ __launch_bounds__(NT, 8) void fused_kernel(
    const float* __restrict__ x,
    const float* __restrict__ Wq, const float* __restrict__ bq,
    const float* __restrict__ Wk, const float* __restrict__ bk,
    const float* __restrict__ Wv, const float* __restrict__ bv,
    const int* __restrict__ edge0, const int* __restrict__ edge1,
    bf16* __restrict__ qws, bf16* __restrict__ kws,
    float* __restrict__ vout, float* __restrict__ denom,
    float* __restrict__ prods, f32x4* __restrict__ attn4,
    unsigned* __restrict__ counter, int n_nodes, int n_edges) {
  const int t = threadIdx.x;
  const int gid = blockIdx.x * NT + t;
  const int nthreads = NB * NT;

  // ---------------- Phase 1: QKV + denom zeroing ----------------
  {
    const int n4 = n_nodes * NHEAD;
    for (int i = gid; i < n4; i += nthreads) denom[i] = 0.f;

    __shared__ float xs[16][64];
    const int ntiles = (n_nodes + 15) / 16;
    for (int tile = blockIdx.x; tile < ntiles; tile += NB) {
      const int base = tile * 16;
      __syncthreads();  // protect xs reuse across tile iterations
#pragma unroll
      for (int j = 0; j < 4; ++j) {
        const int idx = t + NT * j;
        const int nn = idx >> 6, cc = idx & 63;
        xs[nn][cc] = (base + nn < n_nodes)
                         ? __builtin_nontemporal_load(&x[(size_t)(base + nn) * 64 + cc])
                         : 0.f;
      }
      __syncthreads();
      const int c = t & 63;
      const int qg = t >> 6;

      float aq[4], ak[4], av[4];
      const float bqv = bq[c], bkv = bk[c], bvv = bv[c];
#pragma unroll
      for (int j = 0; j < 4; ++j) { aq[j] = bqv; ak[j] = bkv; av[j] = bvv; }
#pragma unroll 4
      for (int r = 0; r < 64; ++r) {
        const float wq = Wq[r * 64 + c];
        const float wk = Wk[r * 64 + c];
        const float wv = Wv[r * 64 + c];
#pragma unroll
        for (int j = 0; j < 4; ++j) {
          const float xv = xs[qg * 4 + j][r];  // wave-uniform -> LDS broadcast
          aq[j] = fmaf(xv, wq, aq[j]);
          ak[j] = fmaf(xv, wk, ak[j]);
          av[j] = fmaf(xv, wv, av[j]);
        }
      }
#pragma unroll
      for (int j = 0; j < 4; ++j) {
        const int node = base + qg * 4 + j;
        if (node < n_nodes) {
          qws[(size_t)node * 64 + c] = __float2bfloat16(aq[j]);
          kws[(size_t)node * 64 + c] = __float2bfloat16(ak[j]);
          vout[(size_t)node * 64 + (c & 15) * 4 + (c >> 4)] = av[j];
        }
      }
    }
  }

  grid_barrier(counter, NB);  // q,k,v,denom=0 visible device-wide

  // ---------------- Phase 2: edge dots + denom atomics ----------------
  {
    const uint4* q4 = (const uint4*)qws;
    const uint4* k4 = (const uint4*)kws;
    const long long npairs = (long long)n_edges * NHEAD;
    for (long long i = gid; i < npairs; i += nthreads) {
      const int e = (int)(i >> 2);
      const int h = (int)(i & 3);
      const int src = __builtin_nontemporal_load(&edge0[e]);
      const int dst = __builtin_nontemporal_load(&edge1[e]);
      // bf16 row = 128B = 8 uint4; head h = slots 2h,2h+1
      const size_t qb = (size_t)src * 8 + h * 2;
      const size_t kb = (size_t)dst * 8 + h * 2;
      const uint4 a0 = q4[qb], a1 = q4[qb + 1];
      const uint4 b0 = k4[kb], b1 = k4[kb + 1];
      const float p = (dot8(a0, b0) + dot8(a1, b1)) * 0.25f;  // 1/sqrt(16)
      prods[i] = p;  // 256B contiguous per wave
      atomicAdd(&denom[(size_t)src * 4 + h], __expf(p));
    }
  }

  grid_barrier(counter, 2 * NB);  // denom sums + prods visible device-wide

  // ---------------- Phase 3: normalize ----------------
  {
    const f32x4* prods4 = (const f32x4*)prods;
    for (int e = gid; e < n_edges; e += nthreads) {
      const int seg = edge0[e];
      const f32x4 p = prods4[e];
      const f32x4 den = *(const f32x4*)&denom[(size_t)seg * 4];
      f32x4 a;
      a.x = __expf(p.x) / (den.x + 1e-16f);
      a.y = __expf(p.y) / (den.y + 1e-16f);
      a.z = __expf(p.z) / (den.z + 1e-16f);
      a.w = __expf(p.w) / (den.w + 1e-16f);
      __builtin_nontemporal_store(a, &attn4[e]);
    }
  }
}

extern "C" void kernel_launch(void* const* d_in, const int* in_sizes, int n_in,
                              void* d_out, int out_size, void* d_ws, size_t ws_size,
                              hipStream_t stream) {
  const float* x  = (const float*)d_in[0];
  const int* edge = (const int*)d_in[1];
  const float* Wq = (const float*)d_in[2];
  const float* bq = (const float*)d_in[3];
  const float* Wk = (const float*)d_in[4];
  const float* bk = (const float*)d_in[5];
  const float* Wv = (const float*)d_in[6];
  const float* bv = (const float*)d_in[7];

  const int n_nodes = in_sizes[0] / 64;   // 50000
  const int n_edges = in_sizes[1] / 2;    // 1600000
  const int* edge0 = edge;
  const int* edge1 = edge + n_edges;

  // Output: attention [E*4] | v [N*64] | prods [E*4]
  float* out_attn  = (float*)d_out;
  float* out_v     = out_attn + (long long)n_edges * NHEAD;
  float* out_prods = out_v + (long long)n_nodes * 64;

  // Workspace: q bf16 [N][64] | k bf16 [N][64] | denom f32 [N][4] | counter
  bf16* ws_q = (bf16*)d_ws;
  bf16* ws_k = ws_q + (size_t)n_nodes * 64;
  float* ws_denom = (float*)(ws_k + (size_t)n_nodes * 64);
  unsigned* ws_counter = (unsigned*)(ws_denom + (size_t)n_nodes * NHEAD);

  hipMemsetAsync(ws_counter, 0, sizeof(unsigned), stream);

  fused_kernel<<<NB, NT, 0, stream>>>(
      x, Wq, bq, Wk, bk, Wv, bv, edge0, edge1,
      ws_q, ws_k, out_v, ws_denom, out_prods, (f32x4*)out_attn,
      ws_counter, n_nodes, n_edges);
}

// Round 11
// 503.160 us; speedup vs baseline: 3.0924x; 3.0924x over previous
//
#include <hip/hip_runtime.h>
#include <hip/hip_bf16.h>

#define NHEAD 4
#define NT 256
#define NB 2048  // 8 blocks/CU x 256 CU; co-residency forced by launch_bounds(256,8)
                 // (proven: R10 ran 2048 blocks at 98% occupancy to completion)

typedef __hip_bfloat16 bf16;
typedef __hip_bfloat162 bf162;
typedef float f32x4 __attribute__((ext_vector_type(4)));

// ---------------------------------------------------------------------------
// Kernel 1: fused QKV projection + denom zeroing (R6's proven body).
// q,k bf16 [N][64] (col = h*16+d) -> 128B contiguous per-edge gather rows.
// v fp32 direct to out in [N, d, h].
// ---------------------------------------------------------------------------
__global__ __launch_bounds__(256) void qkv_kernel(
    const float* __restrict__ x,
    const float* __restrict__ Wq, const float* __restrict__ bq,
    const float* __restrict__ Wk, const float* __restrict__ bk,
    const float* __restrict__ Wv, const float* __restrict__ bv,
    bf16* __restrict__ qout, bf16* __restrict__ kout,
    float* __restrict__ vout, float* __restrict__ denom, int n_nodes) {
  const long long gtid = (long long)blockIdx.x * 256 + threadIdx.x;
  if (gtid < (long long)n_nodes * NHEAD) denom[gtid] = 0.f;

  __shared__ float xs[16][64];
  const int t = threadIdx.x;
  const int base = blockIdx.x * 16;
#pragma unroll
  for (int j = 0; j < 4; ++j) {
    const int idx = t + 256 * j;
    const int nn = idx >> 6, cc = idx & 63;
    xs[nn][cc] = (base + nn < n_nodes)
                     ? __builtin_nontemporal_load(&x[(size_t)(base + nn) * 64 + cc])
                     : 0.f;
  }
  __syncthreads();
  const int c = t & 63;
  const int qg = t >> 6;  // wave id

  float aq[4], ak[4], av[4];
  const float bqv = bq[c], bkv = bk[c], bvv = bv[c];
#pragma unroll
  for (int j = 0; j < 4; ++j) { aq[j] = bqv; ak[j] = bkv; av[j] = bvv; }

#pragma unroll 4
  for (int r = 0; r < 64; ++r) {
    const float wq = Wq[r * 64 + c];
    const float wk = Wk[r * 64 + c];
    const float wv = Wv[r * 64 + c];
#pragma unroll
    for (int j = 0; j < 4; ++j) {
      const float xv = xs[qg * 4 + j][r];  // wave-uniform addr -> LDS broadcast
      aq[j] = fmaf(xv, wq, aq[j]);
      ak[j] = fmaf(xv, wk, ak[j]);
      av[j] = fmaf(xv, wv, av[j]);
    }
  }
#pragma unroll
  for (int j = 0; j < 4; ++j) {
    const int node = base + qg * 4 + j;
    if (node < n_nodes) {
      qout[(size_t)node * 64 + c] = __float2bfloat16(aq[j]);
      kout[(size_t)node * 64 + c] = __float2bfloat16(ak[j]);
      vout[(size_t)node * 64 + (c & 15) * 4 + (c >> 4)] = av[j];
    }
  }
}

__device__ __forceinline__ float dot8(uint4 a, uint4 b) {
  const unsigned* pa = &a.x;
  const unsigned* pb = &b.x;
  float acc = 0.f;
#pragma unroll
  for (int i = 0; i < 4; ++i) {
    const float2 fa = __bfloat1622float2(*(const bf162*)&pa[i]);
    const float2 fb = __bfloat1622float2(*(const bf162*)&pb[i]);
    acc = fmaf(fa.x, fb.x, acc);
    acc = fmaf(fa.y, fb.y, acc);
  }
  return acc;
}

// ---------------------------------------------------------------------------
// Kernel 2 (persistent, 2048 co-resident blocks): edge dots + denom atomics,
// ONE grid barrier, then normalize.
//  Phase A: R6's exact proven mapping -- thread=(edge,head), 4 lanes/edge
//   read one contiguous 128B row; the 4 heads' atomics land in one 16B
//   cluster and wave-coalesce to ONE fabric line-touch per edge (the
//   measured ~1.86e10/s wall => ~86us floor). prods stored with REGULAR
//   stores so phase B re-reads hit the same XCD's L2.
//  Barrier v2 (the R10 fix): RELEASE arrival add + RELAXED polls (agent-
//   scope relaxed load bypasses L2 but emits NO per-poll invalidate -- the
//   per-poll ACQUIRE invalidate is what serialized R10 into ~1.4ms),
//   s_sleep backoff, single acquire fence on exit.
//  Phase B: attn[i] = exp(prods[i]) / (denom[seg*4+h]+eps). denom (800KB)
//   L2-resident; attn regular coalesced 256B/wave stores.
// ---------------------------------------------------------------------------
__global__ __launch_bounds__(NT, 8) void edge_norm_kernel(
    const int* __restrict__ edge0, const int* __restrict__ edge1,
    const uint4* __restrict__ q4, const uint4* __restrict__ k4,
    float* __restrict__ prods, float* __restrict__ attn,
    float* __restrict__ denom, unsigned* __restrict__ counter, int n_edges) {
  const int gid = blockIdx.x * NT + threadIdx.x;
  const int nthreads = NB * NT;
  const long long npairs = (long long)n_edges * NHEAD;

  // ---- Phase A: dots + atomics ----
  for (long long i = gid; i < npairs; i += nthreads) {
    const int e = (int)(i >> 2);
    const int h = (int)(i & 3);
    const int src = edge0[e];
    const int dst = edge1[e];
    // bf16 row = 128B = 8 uint4; head h = slots 2h, 2h+1
    const size_t qb = (size_t)src * 8 + h * 2;
    const size_t kb = (size_t)dst * 8 + h * 2;
    const uint4 a0 = q4[qb], a1 = q4[qb + 1];
    const uint4 b0 = k4[kb], b1 = k4[kb + 1];
    const float p = (dot8(a0, b0) + dot8(a1, b1)) * 0.25f;  // 1/sqrt(16)
    prods[i] = p;  // regular store: 256B/wave contiguous, stays L2-hot
    atomicAdd(&denom[(size_t)src * 4 + h], __expf(p));
  }

  // ---- Grid barrier (v2) ----
  __syncthreads();
  if (threadIdx.x == 0) {
    __hip_atomic_fetch_add(counter, 1u, __ATOMIC_RELEASE,
                           __HIP_MEMORY_SCOPE_AGENT);
    while (__hip_atomic_load(counter, __ATOMIC_RELAXED,
                             __HIP_MEMORY_SCOPE_AGENT) < NB)
      __builtin_amdgcn_s_sleep(16);  // ~1024 cyc backoff between polls
    __threadfence();  // acquire: invalidate caches before reading denom/prods
  }
  __syncthreads();

  // ---- Phase B: normalize ----
  for (long long i = gid; i < npairs; i += nthreads) {
    const int e = (int)(i >> 2);
    const int h = (int)(i & 3);
    const int seg = edge0[e];
    const float p = prods[i];                          // L2-hot (same XCD)
    const float den = denom[(size_t)seg * 4 + h];      // 800KB, L2-resident
    attn[i] = __expf(p) / (den + 1e-16f);              // coalesced 256B/wave
  }
}

extern "C" void kernel_launch(void* const* d_in, const int* in_sizes, int n_in,
                              void* d_out, int out_size, void* d_ws, size_t ws_size,
                              hipStream_t stream) {
  const float* x  = (const float*)d_in[0];
  const int* edge = (const int*)d_in[1];
  const float* Wq = (const float*)d_in[2];
  const float* bq = (const float*)d_in[3];
  const float* Wk = (const float*)d_in[4];
  const float* bk = (const float*)d_in[5];
  const float* Wv = (const float*)d_in[6];
  const float* bv = (const float*)d_in[7];

  const int n_nodes = in_sizes[0] / 64;   // 50000
  const int n_edges = in_sizes[1] / 2;    // 1600000
  const int* edge0 = edge;
  const int* edge1 = edge + n_edges;

  // Output: attention [E*4] | v [N*64] | prods [E*4]
  float* out_attn  = (float*)d_out;
  float* out_v     = out_attn + (long long)n_edges * NHEAD;
  float* out_prods = out_v + (long long)n_nodes * 64;

  // Workspace: q bf16 [N][64] | k bf16 [N][64] | denom f32 [N][4] | counter
  bf16* ws_q = (bf16*)d_ws;
  bf16* ws_k = ws_q + (size_t)n_nodes * 64;
  float* ws_denom = (float*)(ws_k + (size_t)n_nodes * 64);
  unsigned* ws_counter = (unsigned*)(ws_denom + (size_t)n_nodes * NHEAD);

  hipMemsetAsync(ws_counter, 0, sizeof(unsigned), stream);

  {
    const int blocks = (n_nodes + 15) / 16;  // 3125; also zeroes denom
    qkv_kernel<<<blocks, 256, 0, stream>>>(x, Wq, bq, Wk, bk, Wv, bv,
                                           ws_q, ws_k, out_v, ws_denom, n_nodes);
  }
  {
    edge_norm_kernel<<<NB, NT, 0, stream>>>(
        edge0, edge1, (const uint4*)ws_q, (const uint4*)ws_k,
        out_prods, out_attn, ws_denom, ws_counter, n_edges);
  }
}